// Round 12
// baseline (195.063 us; speedup 1.0000x reference)
//
#include <hip/hip_runtime.h>
#include <math.h>

#define BB 64
#define RR 6912
#define II 8
#define CC 10
#define OO 16
#define RPB2 48         // routes per block (fused kernel)
#define NCH2 144        // RR / RPB2
#define NG2 6           // 2-route MFMA groups per wave (12 routes/wave x 4 waves)
#define NBLK 1440       // CC * NCH2  (= 8*180, XCD-bijective)
#define MRG_PAD 20
#define WTILE_I4 (RPB2*16)                 // 768 int4 = 12.3 KB W tile
#define PWW (CC*NCH2*BB*OO)                // per-iteration partials
#define PZW (CC*NCH2*BB)
// flag lines (128B-strided): arrCnt[c], arrRep[c][8], cdone[c], rdone[c][8]
#define L_ARR(c)      ((c) * 32)
#define L_ARREP(c,r)  ((10 + (c)*8 + (r)) * 32)
#define L_CD(c)       ((90 + (c)) * 32)
#define L_RD(c,r)     ((100 + (c)*8 + (r)) * 32)
#define FLAGI (180*32)

typedef _Float16 h2 __attribute__((ext_vector_type(2)));
typedef _Float16 half8 __attribute__((ext_vector_type(8)));
typedef float f32x16 __attribute__((ext_vector_type(16)));
union HV { int4 v; h2 h[4]; half8 h8; };

// Returning atomics: RMW executes AT the coherent point; keeping the return
// live forces the returning encoding, so vmcnt drain == global visibility
// (R3/R7/R9/R10-proven). Unique addresses -> zero line contention.
__device__ __forceinline__ void xchf(float* p, float v) {
    float old = __hip_atomic_exchange(p, v, __ATOMIC_RELAXED, __HIP_MEMORY_SCOPE_AGENT);
    asm volatile("" :: "v"(old));
}
__device__ __forceinline__ void xchf2(float* p, float a, float b) {
    union { unsigned long long u; float f[2]; } v;
    v.f[0] = a; v.f[1] = b;
    unsigned long long old = __hip_atomic_exchange((unsigned long long*)p, v.u,
                              __ATOMIC_RELAXED, __HIP_MEMORY_SCOPE_AGENT);
    asm volatile("" :: "v"(old));
}
__device__ __forceinline__ int addi(int* p) {
    return __hip_atomic_fetch_add(p, 1, __ATOMIC_RELAXED, __HIP_MEMORY_SCOPE_AGENT);
}
__device__ __forceinline__ void xchi(int* p, int v) {
    int old = __hip_atomic_exchange(p, v, __ATOMIC_RELAXED, __HIP_MEMORY_SCOPE_AGENT);
    asm volatile("" :: "v"(old));
}
// SLP is a compile-time literal (s_sleep immediate). GUARD bounds the poll so
// rocprof kernel-replay with stale (monotonic) flags falls through.
template <int SLP, int GUARD>
__device__ __forceinline__ void pollge(const int* p, int tgt) {
    int v = __hip_atomic_load(p, __ATOMIC_RELAXED, __HIP_MEMORY_SCOPE_AGENT);
    int g = 0;
    while (v < tgt && ++g < GUARD) {
        __builtin_amdgcn_s_sleep(SLP);
        v = __hip_atomic_load(p, __ATOMIC_RELAXED, __HIP_MEMORY_SCOPE_AGENT);
    }
}

// ---------------- prep kernel (transpose-only, R11-proven) ----------------
__global__ __launch_bounds__(256) void prep_kernel(
    const float* __restrict__ x, int4* __restrict__ xth4,
    int* __restrict__ flags)
{
    __shared__ __align__(16) float4 lds4[64 * 34];
    const int t = threadIdx.x;
    const int bid = blockIdx.x;

    {
        const unsigned idx = (unsigned)bid * 256u + (unsigned)t;
        if (idx < (unsigned)FLAGI) flags[idx] = 0;
    }

    const int rblk = bid >> 2;
    const int bblk = bid & 3;
    const int r0 = rblk * 64, b0 = bblk * 16;
    {
        const int rl = t & 63;
        const int bl0 = t >> 6;
#pragma unroll
        for (int kb = 0; kb < 4; ++kb) {
            const int bl = kb * 4 + bl0;
            const float4* src = (const float4*)(x + ((size_t)(b0 + bl) * RR + (r0 + rl)) * II);
            lds4[rl * 34 + bl * 2 + 0] = src[0];
            lds4[rl * 34 + bl * 2 + 1] = src[1];
        }
    }
    __syncthreads();
    {
        const int bl = t & 15;
        const int rw0 = t >> 4;
#pragma unroll
        for (int kr = 0; kr < 4; ++kr) {
            const int rw = kr * 16 + rw0;
            float4 a = lds4[rw * 34 + bl * 2 + 0];
            float4 bq = lds4[rw * 34 + bl * 2 + 1];
            HV u;
            u.h[0] = h2{(_Float16)a.x,  (_Float16)a.y};
            u.h[1] = h2{(_Float16)a.z,  (_Float16)a.w};
            u.h[2] = h2{(_Float16)bq.x, (_Float16)bq.y};
            u.h[3] = h2{(_Float16)bq.z, (_Float16)bq.w};
            xth4[(size_t)(r0 + rw) * BB + (b0 + bl)] = u.v;
        }
    }
}

// ---------------- routing iteration ----------------
// MFMA core identical to R7-R11 (passed). Two-half LDS merge (waves 0-1 then
// 2-3 share one 10.2KB buffer) halves LDS so 6 blocks/CU fit -> grid 1440 all
// co-resident at ~70% occupancy (R12 lever: occupancy was grid-capped).
template <int MODE>
__device__ __forceinline__ void it_phase(
    const int4* __restrict__ xth4, const int4* wlds, float* mrg, float* zl,
    const float* __restrict__ ov,
    float* __restrict__ pw, float* __restrict__ pz,
    int* flags, int c, int chunk, int xcd, int t, int ph)
{
    const int wv = t >> 6;
    const int l = t & 63;
    const int b = l & 31;
    const int hi = l >> 5;
    const int aquad = (l >> 4) & 1;
    const bool aact = (aquad == hi);

    if (MODE != 0) {
        if (t == 0) pollge<8, (1 << 14)>(flags + L_RD(c, xcd), ph - 1);
        __syncthreads();   // fence: ov loads stay below the poll
    }

    float accA[8], accB[8];
#pragma unroll
    for (int j = 0; j < 8; ++j) { accA[j] = 0.f; accB[j] = 0.f; }
    float ZA = 0.f, ZB = 0.f;

    float ovA[8], ovB[8];
    if (MODE != 0) {
        const float* pa = ov + ((size_t)c * BB + b) * OO + 4 * hi;
        const float* pb = ov + ((size_t)c * BB + 32 + b) * OO + 4 * hi;
        float4 a0 = *(const float4*)(pa);
        float4 a1 = *(const float4*)(pa + 8);
        float4 b0 = *(const float4*)(pb);
        float4 b1 = *(const float4*)(pb + 8);
        ovA[0]=a0.x; ovA[1]=a0.y; ovA[2]=a0.z; ovA[3]=a0.w;
        ovA[4]=a1.x; ovA[5]=a1.y; ovA[6]=a1.z; ovA[7]=a1.w;
        ovB[0]=b0.x; ovB[1]=b0.y; ovB[2]=b0.z; ovB[3]=b0.w;
        ovB[4]=b1.x; ovB[5]=b1.y; ovB[6]=b1.z; ovB[7]=b1.w;
    }

    const int rbase = chunk * RPB2 + wv * (RPB2 / 4);

    f32x16 cA, cB, zf;
#pragma unroll
    for (int q = 0; q < 16; ++q) { cA[q] = 0.f; cB[q] = 0.f; zf[q] = 0.f; }

    HV xc0, xc1, xn0, xn1;
    xc0.v = xth4[(size_t)(rbase + hi) * BB + b];
    xc1.v = xth4[(size_t)(rbase + hi) * BB + 32 + b];
    xn0 = xc0; xn1 = xc1;

#pragma unroll 1
    for (int g = 0; g < NG2; ++g) {
        if (g + 1 < NG2) {
            const int rn = rbase + (g + 1) * 2 + hi;
            xn0.v = xth4[(size_t)rn * BB + b];
            xn1.v = xth4[(size_t)rn * BB + 32 + b];
        }
        const int rl0 = wv * (RPB2 / 4) + g * 2;
        HV wq;
        wq.v = wlds[(rl0 + aquad) * 16 + (l & 15)];
        if (!aact) wq.v = make_int4(0, 0, 0, 0);

        if (MODE == 0) {
            cA = __builtin_amdgcn_mfma_f32_32x32x16_f16(wq.h8, xc0.h8, cA, 0, 0, 0);
            cB = __builtin_amdgcn_mfma_f32_32x32x16_f16(wq.h8, xc1.h8, cB, 0, 0, 0);
        } else {
            f32x16 p0 = __builtin_amdgcn_mfma_f32_32x32x16_f16(wq.h8, xc0.h8, zf, 0, 0, 0);
            f32x16 p1 = __builtin_amdgcn_mfma_f32_32x32x16_f16(wq.h8, xc1.h8, zf, 0, 0, 0);
            float dA0 = 0.f, dA1 = 0.f, dB0 = 0.f, dB1 = 0.f;
#pragma unroll
            for (int j = 0; j < 8; ++j) {
                dA0 = fmaf(p0[j],     ovA[j], dA0);
                dA1 = fmaf(p0[j + 8], ovA[j], dA1);
                dB0 = fmaf(p1[j],     ovB[j], dB0);
                dB1 = fmaf(p1[j + 8], ovB[j], dB1);
            }
            dA0 += __shfl_xor(dA0, 32);
            dA1 += __shfl_xor(dA1, 32);
            dB0 += __shfl_xor(dB0, 32);
            dB1 += __shfl_xor(dB1, 32);
            const float eA0 = __expf(dA0), eA1 = __expf(dA1);
            const float eB0 = __expf(dB0), eB1 = __expf(dB1);
            ZA += eA0 + eA1; ZB += eB0 + eB1;
#pragma unroll
            for (int j = 0; j < 8; ++j) {
                accA[j] = fmaf(eA0, p0[j], fmaf(eA1, p0[j + 8], accA[j]));
                accB[j] = fmaf(eB0, p1[j], fmaf(eB1, p1[j + 8], accB[j]));
            }
        }
        xc0 = xn0; xc1 = xn1;
    }

    if (MODE == 0) {
#pragma unroll
        for (int j = 0; j < 8; ++j) {
            accA[j] = cA[j] + cA[j + 8];
            accB[j] = cB[j] + cB[j + 8];
        }
    }

    // ---- two-half merge: waves 0,1 -> read -> waves 2,3 -> read+add ----
    if (MODE != 0 && hi == 0) {            // Z rows (tiny separate buffer)
        zl[wv * 64 + b] = ZA;
        zl[wv * 64 + 32 + b] = ZB;
    }
    if (wv < 2) {
        float* m0 = mrg + (wv * 64 + b) * MRG_PAD + 4 * hi;
        *(float4*)(m0)     = make_float4(accA[0], accA[1], accA[2], accA[3]);
        *(float4*)(m0 + 8) = make_float4(accA[4], accA[5], accA[6], accA[7]);
        float* m1 = mrg + (wv * 64 + 32 + b) * MRG_PAD + 4 * hi;
        *(float4*)(m1)     = make_float4(accB[0], accB[1], accB[2], accB[3]);
        *(float4*)(m1 + 8) = make_float4(accB[4], accB[5], accB[6], accB[7]);
    }
    __syncthreads();

    const int b2 = t >> 2, q = t & 3;
    float4 sum = make_float4(0.f, 0.f, 0.f, 0.f);
#pragma unroll
    for (int w2 = 0; w2 < 2; ++w2) {
        const float4 v = *(const float4*)(mrg + (w2 * 64 + b2) * MRG_PAD + q * 4);
        sum.x += v.x; sum.y += v.y; sum.z += v.z; sum.w += v.w;
    }
    __syncthreads();   // all reads of half A done before overwrite

    if (wv >= 2) {
        float* m0 = mrg + ((wv - 2) * 64 + b) * MRG_PAD + 4 * hi;
        *(float4*)(m0)     = make_float4(accA[0], accA[1], accA[2], accA[3]);
        *(float4*)(m0 + 8) = make_float4(accA[4], accA[5], accA[6], accA[7]);
        float* m1 = mrg + ((wv - 2) * 64 + 32 + b) * MRG_PAD + 4 * hi;
        *(float4*)(m1)     = make_float4(accB[0], accB[1], accB[2], accB[3]);
        *(float4*)(m1 + 8) = make_float4(accB[4], accB[5], accB[6], accB[7]);
    }
    __syncthreads();

    {
#pragma unroll
        for (int w2 = 0; w2 < 2; ++w2) {
            const float4 v = *(const float4*)(mrg + (w2 * 64 + b2) * MRG_PAD + q * 4);
            sum.x += v.x; sum.y += v.y; sum.z += v.z; sum.w += v.w;
        }
        // unique slots, transposed layout pw[c][b][chunk][o] (combine reads
        // a contiguous 144x16 run per (c,b))
        float* dst = pw + (((size_t)(c * BB + b2) * NCH2 + chunk) * OO) + q * 4;
        xchf2(dst + 0, sum.x, sum.y);
        xchf2(dst + 2, sum.z, sum.w);
        if (MODE != 0 && q == 0) {
            float z = 0.f;
#pragma unroll
            for (int w2 = 0; w2 < 4; ++w2) z += zl[w2 * 64 + b2];
            xchf(pz + (size_t)(c * BB + b2) * NCH2 + chunk, z);
        }
    }

    __syncthreads();   // drain exchange acks (vmcnt) before arrival
    if (t == 0) {
        const int old = addi(flags + L_ARR(c));
        if (old == NCH2 * ph - 1) {
#pragma unroll
            for (int r = 0; r < 8; ++r) xchi(flags + L_ARREP(c, r), ph);
        }
    }
}

// ---------------- combine: block (c2,b2)=bid sums 144 chunk partials + squash ----------------
template <int MODE>
__device__ __forceinline__ void combine_phase(
    const float* __restrict__ pw, const float* __restrict__ pzw,
    const float* __restrict__ addv, float* __restrict__ dst, bool coh,
    int* flags, int bid, int t, float* cl, int ph)
{
    const int c2 = bid >> 6, b2 = bid & 63;
    const int o = t & 15, g = t >> 4;

    if (t == 0) pollge<8, (1 << 14)>(flags + L_ARREP(c2, bid & 7), ph);
    __syncthreads();   // fence: partial loads stay below the poll

    const float* base = pw + (size_t)(c2 * BB + b2) * NCH2 * OO;
    const float* zb   = pzw + (size_t)(c2 * BB + b2) * NCH2;
    float s = 0.f, zl = 0.f;
#pragma unroll
    for (int k = 0; k < NCH2 / 16; ++k) {
        const int rid = g + k * 16;
        s += base[rid * OO + o];
        if (MODE != 0 && o == 0) zl += zb[rid];
    }
    cl[t] = s;
    if (MODE != 0 && o == 0) cl[256 + g] = zl;
    __syncthreads();

    if (g == 0) {
#pragma unroll
        for (int k = 1; k < 16; ++k) s += cl[k * 16 + o];
        if (MODE != 0) {
            float Zt = 0.f;
#pragma unroll
            for (int k = 0; k < 16; ++k) Zt += cl[256 + k];
            s /= Zt;
        } else {
            s *= (1.0f / RR);
        }
        float sq = s * s;
#pragma unroll
        for (int w = 1; w < 16; w <<= 1) sq += __shfl_xor(sq, w);
        float val = s * sqrtf(sq) / (1.f + sq);
        if (MODE == 1) val += addv[(size_t)bid * OO + o];
        if (coh) xchf(dst + (size_t)bid * OO + o, val);
        else     dst[(size_t)bid * OO + o] = val;   // final out: dispatch-end flush
    }
    __syncthreads();   // drain v-write acks before completion count

    if (MODE != 2 && t == 0) {
        const int old = addi(flags + L_CD(c2));
        if (old == 64 * ph - 1) {                // 64 combine blocks per class
#pragma unroll
            for (int r = 0; r < 8; ++r) xchi(flags + L_RD(c2, r), ph);
        }
    }
}

// ---------------- fused routing kernel ----------------
// 1440 blocks, all co-resident: LDS 24.6KB -> 6 blocks/CU (capacity 1536),
// launch_bounds(256,6) caps VGPR at ~84 (we use ~70). ~70% occupancy vs
// R11's 35% (occupancy was grid-capped - R12 lever). W staged once from f32.
// XCD swizzle: 1440 = 8*180, 180%10==0 -> bijective, chunk-mates share XCD.
__global__ __launch_bounds__(256, 6) void fused_kernel(
    const int4* __restrict__ xth4, const float* __restrict__ w,
    float* pw0, float* pw1, float* pw2, float* pz1, float* pz2,
    float* v0, float* outsum, float* out, int* flags)
{
    __shared__ __align__(16) int4 wlds[WTILE_I4];       // 12288 B
    __shared__ __align__(16) float mrg[2 * 64 * MRG_PAD]; // 10240 B
    __shared__ float zl[256];                           //  1024 B
    __shared__ float cl[272];                           //  1088 B

    const int bid = blockIdx.x;
    const int t = threadIdx.x;
    const int xcd = bid & 7;
    const int u = xcd * 180 + (bid >> 3);
    const int chunk = u / 10;
    const int c = u - chunk * 10;

    // stage the 48-route W tile f32 -> f16 [r][o][i] in LDS (6x256 float4)
    {
        const float4* wsrc = (const float4*)(w + ((size_t)c * RR + (size_t)chunk * RPB2) * 128);
        _Float16* wl = (_Float16*)wlds;
        const int i  = (t >> 2) & 7;
        const int o0 = (t & 3) * 4;
#pragma unroll
        for (int p = 0; p < 6; ++p) {
            const float4 v = wsrc[p * 256 + t];
            const int rp = (p * 256 + t) >> 5;
            wl[(rp * 16 + o0 + 0) * 8 + i] = (_Float16)v.x;
            wl[(rp * 16 + o0 + 1) * 8 + i] = (_Float16)v.y;
            wl[(rp * 16 + o0 + 2) * 8 + i] = (_Float16)v.z;
            wl[(rp * 16 + o0 + 3) * 8 + i] = (_Float16)v.w;
        }
    }
    __syncthreads();

    it_phase<0>(xth4, wlds, mrg, zl, nullptr, pw0, nullptr, flags, c, chunk, xcd, t, 1);
    if (bid < CC * BB) combine_phase<0>(pw0, nullptr, nullptr, v0, true, flags, bid, t, cl, 1);
    it_phase<1>(xth4, wlds, mrg, zl, v0, pw1, pz1, flags, c, chunk, xcd, t, 2);
    if (bid < CC * BB) combine_phase<1>(pw1, pz1, v0, outsum, true, flags, bid, t, cl, 2);
    it_phase<2>(xth4, wlds, mrg, zl, outsum, pw2, pz2, flags, c, chunk, xcd, t, 3);
    if (bid < CC * BB) combine_phase<2>(pw2, pz2, nullptr, out, false, flags, bid, t, cl, 3);
}

extern "C" void kernel_launch(void* const* d_in, const int* in_sizes, int n_in,
                              void* d_out, int out_size, void* d_ws, size_t ws_size,
                              hipStream_t stream)
{
    const float* x = (const float*)d_in[0];
    const float* w = (const float*)d_in[1];
    float* out = (float*)d_out;

    float* ws = (float*)d_ws;
    float* xth    = ws;                                   // RR*BB*4 f32 slots (f16 x2)
    float* pw0    = xth + (size_t)RR * BB * 4;            // PWW
    float* pw1    = pw0 + PWW;                            // PWW
    float* pw2    = pw1 + PWW;                            // PWW
    float* pz1    = pw2 + PWW;                            // PZW
    float* pz2    = pz1 + PZW;                            // PZW
    float* v0     = pz2 + PZW;                            // CC*BB*OO
    float* outsum = v0 + CC * BB * OO;                    // CC*BB*OO
    int*   flags  = (int*)(outsum + CC * BB * OO);        // FLAGI ints

    int4* xth4 = (int4*)xth;

    prep_kernel<<<dim3(432), dim3(256), 0, stream>>>(x, xth4, flags);
    fused_kernel<<<dim3(NBLK), dim3(256), 0, stream>>>(
        xth4, w, pw0, pw1, pw2, pz1, pz2, v0, outsum, out, flags);
}

// Round 13
// 150.406 us; speedup vs baseline: 1.2969x; 1.2969x over previous
//
#include <hip/hip_runtime.h>
#include <math.h>

#define BB 64
#define RR 6912
#define II 8
#define CC 10
#define OO 16
#define RPB2 96         // routes per block (fused kernel)
#define NCH2 72         // RR / RPB2
#define NG2 12          // 2-route MFMA groups per wave (24 routes/wave x 4 waves)
#define NBLK 720        // CC * NCH2  (= 8*90, XCD-bijective)
#define MRG_PAD 20
#define WTILE_I4 (RPB2*16)                 // 1536 int4 = 24 KB W tile
#define MRGF (4*64*MRG_PAD + 4*64)         // 5376 floats merge scratch
#define PWW (CC*NCH2*BB*OO)                // per-iteration partials (737280 f32)
#define PZW (CC*NCH2*BB)                   // 46080 f32
// flag lines (128B-strided): arrCnt[c], arrRep[c][8], cdone[c], rdone[c][8]
#define L_ARR(c)      ((c) * 32)
#define L_ARREP(c,r)  ((10 + (c)*8 + (r)) * 32)
#define L_CD(c)       ((90 + (c)) * 32)
#define L_RD(c,r)     ((100 + (c)*8 + (r)) * 32)
#define FLAGI (180*32)

typedef _Float16 h2 __attribute__((ext_vector_type(2)));
typedef _Float16 half8 __attribute__((ext_vector_type(8)));
typedef float f32x16 __attribute__((ext_vector_type(16)));
union HV { int4 v; h2 h[4]; half8 h8; };

// Returning atomics: RMW executes AT the coherent point; keeping the return
// live forces the returning encoding, so vmcnt drain == global visibility
// (R3/R7/R9/R10-proven). Unique addresses -> zero line contention.
__device__ __forceinline__ void xchf(float* p, float v) {
    float old = __hip_atomic_exchange(p, v, __ATOMIC_RELAXED, __HIP_MEMORY_SCOPE_AGENT);
    asm volatile("" :: "v"(old));
}
__device__ __forceinline__ void xchf2(float* p, float a, float b) {
    union { unsigned long long u; float f[2]; } v;
    v.f[0] = a; v.f[1] = b;
    unsigned long long old = __hip_atomic_exchange((unsigned long long*)p, v.u,
                              __ATOMIC_RELAXED, __HIP_MEMORY_SCOPE_AGENT);
    asm volatile("" :: "v"(old));
}
__device__ __forceinline__ int addi(int* p) {
    return __hip_atomic_fetch_add(p, 1, __ATOMIC_RELAXED, __HIP_MEMORY_SCOPE_AGENT);
}
__device__ __forceinline__ void xchi(int* p, int v) {
    int old = __hip_atomic_exchange(p, v, __ATOMIC_RELAXED, __HIP_MEMORY_SCOPE_AGENT);
    asm volatile("" :: "v"(old));
}
// SLP is a compile-time literal (s_sleep immediate). GUARD bounds the poll so
// rocprof kernel-replay with stale (monotonic) flags falls through.
template <int SLP, int GUARD>
__device__ __forceinline__ void pollge(const int* p, int tgt) {
    int v = __hip_atomic_load(p, __ATOMIC_RELAXED, __HIP_MEMORY_SCOPE_AGENT);
    int g = 0;
    while (v < tgt && ++g < GUARD) {
        __builtin_amdgcn_s_sleep(SLP);
        v = __hip_atomic_load(p, __ATOMIC_RELAXED, __HIP_MEMORY_SCOPE_AGENT);
    }
}

// ---------------- prep kernel (transpose-only, R11-proven) ----------------
__global__ __launch_bounds__(256) void prep_kernel(
    const float* __restrict__ x, int4* __restrict__ xth4,
    int* __restrict__ flags)
{
    __shared__ __align__(16) float4 lds4[64 * 34];
    const int t = threadIdx.x;
    const int bid = blockIdx.x;

    {
        const unsigned idx = (unsigned)bid * 256u + (unsigned)t;
        if (idx < (unsigned)FLAGI) flags[idx] = 0;
    }

    const int rblk = bid >> 2;
    const int bblk = bid & 3;
    const int r0 = rblk * 64, b0 = bblk * 16;
    {
        const int rl = t & 63;
        const int bl0 = t >> 6;
#pragma unroll
        for (int kb = 0; kb < 4; ++kb) {
            const int bl = kb * 4 + bl0;
            const float4* src = (const float4*)(x + ((size_t)(b0 + bl) * RR + (r0 + rl)) * II);
            lds4[rl * 34 + bl * 2 + 0] = src[0];
            lds4[rl * 34 + bl * 2 + 1] = src[1];
        }
    }
    __syncthreads();
    {
        const int bl = t & 15;
        const int rw0 = t >> 4;
#pragma unroll
        for (int kr = 0; kr < 4; ++kr) {
            const int rw = kr * 16 + rw0;
            float4 a = lds4[rw * 34 + bl * 2 + 0];
            float4 bq = lds4[rw * 34 + bl * 2 + 1];
            HV u;
            u.h[0] = h2{(_Float16)a.x,  (_Float16)a.y};
            u.h[1] = h2{(_Float16)a.z,  (_Float16)a.w};
            u.h[2] = h2{(_Float16)bq.x, (_Float16)bq.y};
            u.h[3] = h2{(_Float16)bq.z, (_Float16)bq.w};
            xth4[(size_t)(r0 + rw) * BB + (b0 + bl)] = u.v;
        }
    }
}

// ---------------- routing iteration ----------------
// MFMA core identical to R7-R11 (passed), but x fragments come from the
// REGISTER arrays xr0/xr1 loaded once in the kernel body (R13 lever: x was
// re-loaded from L2 identically in every iteration with depth-1 prefetch at
// 3 waves/SIMD -> exposed latency). Group loop fully unrolled (static idx).
template <int MODE>
__device__ __forceinline__ void it_phase(
    const HV* xr0, const HV* xr1, const int4* wlds, float* mrg,
    const float* __restrict__ ov,
    float* __restrict__ pw, float* __restrict__ pz,
    int* flags, int c, int chunk, int xcd, int t, int ph)
{
    const int wv = t >> 6;
    const int l = t & 63;
    const int b = l & 31;
    const int hi = l >> 5;
    const int aquad = (l >> 4) & 1;
    const bool aact = (aquad == hi);

    if (MODE != 0) {
        if (t == 0) pollge<8, (1 << 14)>(flags + L_RD(c, xcd), ph - 1);
        __syncthreads();   // fence: ov loads stay below the poll
    }

    float accA[8], accB[8];
#pragma unroll
    for (int j = 0; j < 8; ++j) { accA[j] = 0.f; accB[j] = 0.f; }
    float ZA = 0.f, ZB = 0.f;

    float ovA[8], ovB[8];
    if (MODE != 0) {
        const float* pa = ov + ((size_t)c * BB + b) * OO + 4 * hi;
        const float* pb = ov + ((size_t)c * BB + 32 + b) * OO + 4 * hi;
        float4 a0 = *(const float4*)(pa);
        float4 a1 = *(const float4*)(pa + 8);
        float4 b0 = *(const float4*)(pb);
        float4 b1 = *(const float4*)(pb + 8);
        ovA[0]=a0.x; ovA[1]=a0.y; ovA[2]=a0.z; ovA[3]=a0.w;
        ovA[4]=a1.x; ovA[5]=a1.y; ovA[6]=a1.z; ovA[7]=a1.w;
        ovB[0]=b0.x; ovB[1]=b0.y; ovB[2]=b0.z; ovB[3]=b0.w;
        ovB[4]=b1.x; ovB[5]=b1.y; ovB[6]=b1.z; ovB[7]=b1.w;
    }

    f32x16 cA, cB, zf;
#pragma unroll
    for (int q = 0; q < 16; ++q) { cA[q] = 0.f; cB[q] = 0.f; zf[q] = 0.f; }

#pragma unroll
    for (int g = 0; g < NG2; ++g) {
        HV xc0 = xr0[g], xc1 = xr1[g];     // registers, no loads
        const int rl0 = wv * 24 + g * 2;
        HV wq;
        wq.v = wlds[(rl0 + aquad) * 16 + (l & 15)];
        if (!aact) wq.v = make_int4(0, 0, 0, 0);

        if (MODE == 0) {
            cA = __builtin_amdgcn_mfma_f32_32x32x16_f16(wq.h8, xc0.h8, cA, 0, 0, 0);
            cB = __builtin_amdgcn_mfma_f32_32x32x16_f16(wq.h8, xc1.h8, cB, 0, 0, 0);
        } else {
            f32x16 p0 = __builtin_amdgcn_mfma_f32_32x32x16_f16(wq.h8, xc0.h8, zf, 0, 0, 0);
            f32x16 p1 = __builtin_amdgcn_mfma_f32_32x32x16_f16(wq.h8, xc1.h8, zf, 0, 0, 0);
            float dA0 = 0.f, dA1 = 0.f, dB0 = 0.f, dB1 = 0.f;
#pragma unroll
            for (int j = 0; j < 8; ++j) {
                dA0 = fmaf(p0[j],     ovA[j], dA0);
                dA1 = fmaf(p0[j + 8], ovA[j], dA1);
                dB0 = fmaf(p1[j],     ovB[j], dB0);
                dB1 = fmaf(p1[j + 8], ovB[j], dB1);
            }
            dA0 += __shfl_xor(dA0, 32);
            dA1 += __shfl_xor(dA1, 32);
            dB0 += __shfl_xor(dB0, 32);
            dB1 += __shfl_xor(dB1, 32);
            const float eA0 = __expf(dA0), eA1 = __expf(dA1);
            const float eB0 = __expf(dB0), eB1 = __expf(dB1);
            ZA += eA0 + eA1; ZB += eB0 + eB1;
#pragma unroll
            for (int j = 0; j < 8; ++j) {
                accA[j] = fmaf(eA0, p0[j], fmaf(eA1, p0[j + 8], accA[j]));
                accB[j] = fmaf(eB0, p1[j], fmaf(eB1, p1[j + 8], accB[j]));
            }
        }
    }

    if (MODE == 0) {
#pragma unroll
        for (int j = 0; j < 8; ++j) {
            accA[j] = cA[j] + cA[j + 8];
            accB[j] = cB[j] + cB[j + 8];
        }
    }

    {
        float* m0 = mrg + (wv * 64 + b) * MRG_PAD + 4 * hi;
        *(float4*)(m0)     = make_float4(accA[0], accA[1], accA[2], accA[3]);
        *(float4*)(m0 + 8) = make_float4(accA[4], accA[5], accA[6], accA[7]);
        float* m1 = mrg + (wv * 64 + 32 + b) * MRG_PAD + 4 * hi;
        *(float4*)(m1)     = make_float4(accB[0], accB[1], accB[2], accB[3]);
        *(float4*)(m1 + 8) = make_float4(accB[4], accB[5], accB[6], accB[7]);
        if (MODE != 0 && hi == 0) {
            float* zr = mrg + 4 * 64 * MRG_PAD;
            zr[wv * 64 + b] = ZA;
            zr[wv * 64 + 32 + b] = ZB;
        }
    }
    __syncthreads();

    // block partial -> unique slots, transposed layout pw[c][b][chunk][o]
    // (combine block (c,b) reads a contiguous 72x16 f32 run)
    {
        const int b2 = t >> 2, q = t & 3;
        float4 sum = make_float4(0.f, 0.f, 0.f, 0.f);
#pragma unroll
        for (int w2 = 0; w2 < 4; ++w2) {
            const float4 v = *(const float4*)(mrg + (w2 * 64 + b2) * MRG_PAD + q * 4);
            sum.x += v.x; sum.y += v.y; sum.z += v.z; sum.w += v.w;
        }
        float* dst = pw + (((size_t)(c * BB + b2) * NCH2 + chunk) * OO) + q * 4;
        xchf2(dst + 0, sum.x, sum.y);
        xchf2(dst + 2, sum.z, sum.w);
        if (MODE != 0 && q == 0) {
            const float* zr = mrg + 4 * 64 * MRG_PAD;
            float z = 0.f;
#pragma unroll
            for (int w2 = 0; w2 < 4; ++w2) z += zr[w2 * 64 + b2];
            xchf(pz + (size_t)(c * BB + b2) * NCH2 + chunk, z);
        }
    }

    __syncthreads();   // drain exchange acks (vmcnt) before arrival
    if (t == 0) {
        const int old = addi(flags + L_ARR(c));
        if (old == NCH2 * ph - 1) {
#pragma unroll
            for (int r = 0; r < 8; ++r) xchi(flags + L_ARREP(c, r), ph);
        }
    }
}

// ---------------- combine: block (c2,b2)=bid sums 72 chunk partials + squash ----------------
template <int MODE>
__device__ __forceinline__ void combine_phase(
    const float* __restrict__ pw, const float* __restrict__ pzw,
    const float* __restrict__ addv, float* __restrict__ dst, bool coh,
    int* flags, int bid, int t, float* cl, int ph)
{
    const int c2 = bid >> 6, b2 = bid & 63;
    const int o = t & 15, g = t >> 4;

    if (t == 0) pollge<8, (1 << 14)>(flags + L_ARREP(c2, bid & 7), ph);
    __syncthreads();   // fence: partial loads stay below the poll

    // contiguous 72x16 run for this (c2,b2)
    const float* base = pw + (size_t)(c2 * BB + b2) * NCH2 * OO;
    const float* zb   = pzw + (size_t)(c2 * BB + b2) * NCH2;
    float s = 0.f, zl = 0.f;
#pragma unroll
    for (int k = 0; k < 5; ++k) {
        const int rid = g + k * 16;
        if (rid < NCH2) {
            s += base[rid * OO + o];
            if (MODE != 0 && o == 0) zl += zb[rid];
        }
    }
    cl[t] = s;
    if (MODE != 0 && o == 0) cl[256 + g] = zl;
    __syncthreads();

    if (g == 0) {
#pragma unroll
        for (int k = 1; k < 16; ++k) s += cl[k * 16 + o];
        if (MODE != 0) {
            float Zt = 0.f;
#pragma unroll
            for (int k = 0; k < 16; ++k) Zt += cl[256 + k];
            s /= Zt;
        } else {
            s *= (1.0f / RR);
        }
        float sq = s * s;
#pragma unroll
        for (int w = 1; w < 16; w <<= 1) sq += __shfl_xor(sq, w);
        float val = s * sqrtf(sq) / (1.f + sq);
        if (MODE == 1) val += addv[(size_t)bid * OO + o];
        if (coh) xchf(dst + (size_t)bid * OO + o, val);
        else     dst[(size_t)bid * OO + o] = val;   // final out: dispatch-end flush
    }
    __syncthreads();   // drain v-write acks before completion count

    if (MODE != 2 && t == 0) {
        const int old = addi(flags + L_CD(c2));
        if (old == 64 * ph - 1) {                // 64 combine blocks per class
#pragma unroll
            for (int r = 0; r < 8; ++r) xchi(flags + L_RD(c2, r), ph);
        }
    }
}

// ---------------- fused routing kernel ----------------
// R11 config (720 blocks, 3/CU, LDS 47.2KB — R12's 6/CU grid falsified:
// handoff traffic exploded). NEW: x fragments register-cached across all 3
// iterations (24 x int4 = 96 VGPR; total ~150 < 168 cap of (256,3)).
// W staged once from f32 (R11). XCD swizzle u=(bid&7)*90+(bid>>3) (R9).
// Producer-consumer flags, <=9 pollers/line (R10).
__global__ __launch_bounds__(256, 3) void fused_kernel(
    const int4* __restrict__ xth4, const float* __restrict__ w,
    float* pw0, float* pw1, float* pw2, float* pz1, float* pz2,
    float* v0, float* outsum, float* out, int* flags)
{
    __shared__ __align__(16) int4 wlds[WTILE_I4];   // 24576 B
    __shared__ __align__(16) float mrg[MRGF];       // 21504 B
    __shared__ float cl[272];                       //  1088 B

    const int bid = blockIdx.x;
    const int t = threadIdx.x;
    const int xcd = bid & 7;
    const int u = xcd * 90 + (bid >> 3);
    const int chunk = u / 10;
    const int c = u - chunk * 10;

    const int wv = t >> 6;
    const int l = t & 63;
    const int b = l & 31;
    const int hi = l >> 5;

    // stage the 96-route W tile f32 -> f16 [r][o][i] in LDS (12x256 float4)
    {
        const float4* wsrc = (const float4*)(w + ((size_t)c * RR + (size_t)chunk * RPB2) * 128);
        _Float16* wl = (_Float16*)wlds;
        const int i  = (t >> 2) & 7;
        const int o0 = (t & 3) * 4;
#pragma unroll 6
        for (int p = 0; p < 12; ++p) {
            const float4 v = wsrc[p * 256 + t];
            const int rp = (p * 256 + t) >> 5;
            wl[(rp * 16 + o0 + 0) * 8 + i] = (_Float16)v.x;
            wl[(rp * 16 + o0 + 1) * 8 + i] = (_Float16)v.y;
            wl[(rp * 16 + o0 + 2) * 8 + i] = (_Float16)v.z;
            wl[(rp * 16 + o0 + 3) * 8 + i] = (_Float16)v.w;
        }
    }

    // load ALL x fragments once into registers (24 independent 16B loads in
    // flight; latency paid once, reused by all 3 iterations)
    HV xr0[NG2], xr1[NG2];
    {
        const int rbase = chunk * RPB2 + wv * 24;
#pragma unroll
        for (int g = 0; g < NG2; ++g) {
            const int rn = rbase + g * 2 + hi;
            xr0[g].v = xth4[(size_t)rn * BB + b];
            xr1[g].v = xth4[(size_t)rn * BB + 32 + b];
        }
    }
    __syncthreads();   // W tile ready (x loads also drained)

    it_phase<0>(xr0, xr1, wlds, mrg, nullptr, pw0, nullptr, flags, c, chunk, xcd, t, 1);
    if (bid < CC * BB) combine_phase<0>(pw0, nullptr, nullptr, v0, true, flags, bid, t, cl, 1);
    it_phase<1>(xr0, xr1, wlds, mrg, v0, pw1, pz1, flags, c, chunk, xcd, t, 2);
    if (bid < CC * BB) combine_phase<1>(pw1, pz1, v0, outsum, true, flags, bid, t, cl, 2);
    it_phase<2>(xr0, xr1, wlds, mrg, outsum, pw2, pz2, flags, c, chunk, xcd, t, 3);
    if (bid < CC * BB) combine_phase<2>(pw2, pz2, nullptr, out, false, flags, bid, t, cl, 3);
}

extern "C" void kernel_launch(void* const* d_in, const int* in_sizes, int n_in,
                              void* d_out, int out_size, void* d_ws, size_t ws_size,
                              hipStream_t stream)
{
    const float* x = (const float*)d_in[0];
    const float* w = (const float*)d_in[1];
    float* out = (float*)d_out;

    float* ws = (float*)d_ws;
    float* xth    = ws;                                   // RR*BB*4 f32 slots (f16 x2)
    float* pw0    = xth + (size_t)RR * BB * 4;            // PWW
    float* pw1    = pw0 + PWW;                            // PWW
    float* pw2    = pw1 + PWW;                            // PWW
    float* pz1    = pw2 + PWW;                            // PZW
    float* pz2    = pz1 + PZW;                            // PZW
    float* v0     = pz2 + PZW;                            // CC*BB*OO
    float* outsum = v0 + CC * BB * OO;                    // CC*BB*OO
    int*   flags  = (int*)(outsum + CC * BB * OO);        // FLAGI ints

    int4* xth4 = (int4*)xth;

    prep_kernel<<<dim3(432), dim3(256), 0, stream>>>(x, xth4, flags);
    fused_kernel<<<dim3(NBLK), dim3(256), 0, stream>>>(
        xth4, w, pw0, pw1, pw2, pz1, pz2, v0, outsum, out, flags);
}

// Round 14
// 135.801 us; speedup vs baseline: 1.4364x; 1.1075x over previous
//
#include <hip/hip_runtime.h>
#include <math.h>

#define BB 64
#define RR 6912
#define II 8
#define CC 10
#define OO 16
#define RPB2 96         // routes per block (fused kernel)
#define NCH2 72         // RR / RPB2
#define NG2 12          // 2-route MFMA groups per wave (24 routes/wave x 4 waves)
#define NGH 6           // groups per register half-batch (R14)
#define NBLK 720        // CC * NCH2  (= 8*90, XCD-bijective)
#define MRG_PAD 20
#define WTILE_I4 (RPB2*16)                 // 1536 int4 = 24 KB W tile
#define MRGF (4*64*MRG_PAD + 4*64)         // 5376 floats merge scratch
#define PWW (CC*NCH2*BB*OO)                // per-iteration partials (737280 f32)
#define PZW (CC*NCH2*BB)                   // 46080 f32
// flag lines (128B-strided): arrCnt[c], arrRep[c][8], cdone[c], rdone[c][8]
#define L_ARR(c)      ((c) * 32)
#define L_ARREP(c,r)  ((10 + (c)*8 + (r)) * 32)
#define L_CD(c)       ((90 + (c)) * 32)
#define L_RD(c,r)     ((100 + (c)*8 + (r)) * 32)
#define FLAGI (180*32)

typedef _Float16 h2 __attribute__((ext_vector_type(2)));
typedef _Float16 half8 __attribute__((ext_vector_type(8)));
typedef float f32x16 __attribute__((ext_vector_type(16)));
union HV { int4 v; h2 h[4]; half8 h8; };

// Returning atomics: RMW executes AT the coherent point; keeping the return
// live forces the returning encoding, so vmcnt drain == global visibility
// (R3/R7/R9/R10-proven). Unique addresses -> zero line contention.
__device__ __forceinline__ void xchf(float* p, float v) {
    float old = __hip_atomic_exchange(p, v, __ATOMIC_RELAXED, __HIP_MEMORY_SCOPE_AGENT);
    asm volatile("" :: "v"(old));
}
__device__ __forceinline__ void xchf2(float* p, float a, float b) {
    union { unsigned long long u; float f[2]; } v;
    v.f[0] = a; v.f[1] = b;
    unsigned long long old = __hip_atomic_exchange((unsigned long long*)p, v.u,
                              __ATOMIC_RELAXED, __HIP_MEMORY_SCOPE_AGENT);
    asm volatile("" :: "v"(old));
}
__device__ __forceinline__ int addi(int* p) {
    return __hip_atomic_fetch_add(p, 1, __ATOMIC_RELAXED, __HIP_MEMORY_SCOPE_AGENT);
}
__device__ __forceinline__ void xchi(int* p, int v) {
    int old = __hip_atomic_exchange(p, v, __ATOMIC_RELAXED, __HIP_MEMORY_SCOPE_AGENT);
    asm volatile("" :: "v"(old));
}
// SLP is a compile-time literal (s_sleep immediate). GUARD bounds the poll so
// rocprof kernel-replay with stale (monotonic) flags falls through.
template <int SLP, int GUARD>
__device__ __forceinline__ void pollge(const int* p, int tgt) {
    int v = __hip_atomic_load(p, __ATOMIC_RELAXED, __HIP_MEMORY_SCOPE_AGENT);
    int g = 0;
    while (v < tgt && ++g < GUARD) {
        __builtin_amdgcn_s_sleep(SLP);
        v = __hip_atomic_load(p, __ATOMIC_RELAXED, __HIP_MEMORY_SCOPE_AGENT);
    }
}

// ---------------- prep kernel (transpose-only, R11-proven) ----------------
__global__ __launch_bounds__(256) void prep_kernel(
    const float* __restrict__ x, int4* __restrict__ xth4,
    int* __restrict__ flags)
{
    __shared__ __align__(16) float4 lds4[64 * 34];
    const int t = threadIdx.x;
    const int bid = blockIdx.x;

    {
        const unsigned idx = (unsigned)bid * 256u + (unsigned)t;
        if (idx < (unsigned)FLAGI) flags[idx] = 0;
    }

    const int rblk = bid >> 2;
    const int bblk = bid & 3;
    const int r0 = rblk * 64, b0 = bblk * 16;
    {
        const int rl = t & 63;
        const int bl0 = t >> 6;
#pragma unroll
        for (int kb = 0; kb < 4; ++kb) {
            const int bl = kb * 4 + bl0;
            const float4* src = (const float4*)(x + ((size_t)(b0 + bl) * RR + (r0 + rl)) * II);
            lds4[rl * 34 + bl * 2 + 0] = src[0];
            lds4[rl * 34 + bl * 2 + 1] = src[1];
        }
    }
    __syncthreads();
    {
        const int bl = t & 15;
        const int rw0 = t >> 4;
#pragma unroll
        for (int kr = 0; kr < 4; ++kr) {
            const int rw = kr * 16 + rw0;
            float4 a = lds4[rw * 34 + bl * 2 + 0];
            float4 bq = lds4[rw * 34 + bl * 2 + 1];
            HV u;
            u.h[0] = h2{(_Float16)a.x,  (_Float16)a.y};
            u.h[1] = h2{(_Float16)a.z,  (_Float16)a.w};
            u.h[2] = h2{(_Float16)bq.x, (_Float16)bq.y};
            u.h[3] = h2{(_Float16)bq.z, (_Float16)bq.w};
            xth4[(size_t)(r0 + rw) * BB + (b0 + bl)] = u.v;
        }
    }
}

// ---------------- routing iteration ----------------
// MFMA core identical to R7-R11 (passed). R14: x loads in TWO half-batches of
// NGH groups, arrays local to this (inlined) phase -> short live range, SROA
// promotes to registers (R13 lesson: cross-phase arrays spilled to scratch,
// FETCH/WRITE +50MB). Latency paid 2x/phase instead of 12x (depth-1 ring) at
// 2.28 waves/SIMD where TLP can't hide it.
template <int MODE>
__device__ __forceinline__ void it_phase(
    const int4* __restrict__ xth4, const int4* wlds, float* mrg,
    const float* __restrict__ ov,
    float* __restrict__ pw, float* __restrict__ pz,
    int* flags, int c, int chunk, int xcd, int t, int ph)
{
    const int wv = t >> 6;
    const int l = t & 63;
    const int b = l & 31;
    const int hi = l >> 5;
    const int aquad = (l >> 4) & 1;
    const bool aact = (aquad == hi);

    if (MODE != 0) {
        if (t == 0) pollge<8, (1 << 14)>(flags + L_RD(c, xcd), ph - 1);
        __syncthreads();   // fence: ov loads stay below the poll
    }

    float accA[8], accB[8];
#pragma unroll
    for (int j = 0; j < 8; ++j) { accA[j] = 0.f; accB[j] = 0.f; }
    float ZA = 0.f, ZB = 0.f;

    float ovA[8], ovB[8];
    if (MODE != 0) {
        const float* pa = ov + ((size_t)c * BB + b) * OO + 4 * hi;
        const float* pb = ov + ((size_t)c * BB + 32 + b) * OO + 4 * hi;
        float4 a0 = *(const float4*)(pa);
        float4 a1 = *(const float4*)(pa + 8);
        float4 b0 = *(const float4*)(pb);
        float4 b1 = *(const float4*)(pb + 8);
        ovA[0]=a0.x; ovA[1]=a0.y; ovA[2]=a0.z; ovA[3]=a0.w;
        ovA[4]=a1.x; ovA[5]=a1.y; ovA[6]=a1.z; ovA[7]=a1.w;
        ovB[0]=b0.x; ovB[1]=b0.y; ovB[2]=b0.z; ovB[3]=b0.w;
        ovB[4]=b1.x; ovB[5]=b1.y; ovB[6]=b1.z; ovB[7]=b1.w;
    }

    const int rbase = chunk * RPB2 + wv * 24;

    f32x16 cA, cB, zf;
#pragma unroll
    for (int q = 0; q < 16; ++q) { cA[q] = 0.f; cB[q] = 0.f; zf[q] = 0.f; }

#pragma unroll
    for (int half = 0; half < 2; ++half) {
        // half-batch: issue NGH x-load pairs (12 independent 16B loads in
        // flight; one latency wait per half instead of per group)
        HV xr0[NGH], xr1[NGH];
#pragma unroll
        for (int g = 0; g < NGH; ++g) {
            const int rn = rbase + (half * NGH + g) * 2 + hi;
            xr0[g].v = xth4[(size_t)rn * BB + b];
            xr1[g].v = xth4[(size_t)rn * BB + 32 + b];
        }

#pragma unroll
        for (int g = 0; g < NGH; ++g) {
            HV xc0 = xr0[g], xc1 = xr1[g];
            const int rl0 = wv * 24 + (half * NGH + g) * 2;
            HV wq;
            wq.v = wlds[(rl0 + aquad) * 16 + (l & 15)];
            if (!aact) wq.v = make_int4(0, 0, 0, 0);

            if (MODE == 0) {
                cA = __builtin_amdgcn_mfma_f32_32x32x16_f16(wq.h8, xc0.h8, cA, 0, 0, 0);
                cB = __builtin_amdgcn_mfma_f32_32x32x16_f16(wq.h8, xc1.h8, cB, 0, 0, 0);
            } else {
                f32x16 p0 = __builtin_amdgcn_mfma_f32_32x32x16_f16(wq.h8, xc0.h8, zf, 0, 0, 0);
                f32x16 p1 = __builtin_amdgcn_mfma_f32_32x32x16_f16(wq.h8, xc1.h8, zf, 0, 0, 0);
                float dA0 = 0.f, dA1 = 0.f, dB0 = 0.f, dB1 = 0.f;
#pragma unroll
                for (int j = 0; j < 8; ++j) {
                    dA0 = fmaf(p0[j],     ovA[j], dA0);
                    dA1 = fmaf(p0[j + 8], ovA[j], dA1);
                    dB0 = fmaf(p1[j],     ovB[j], dB0);
                    dB1 = fmaf(p1[j + 8], ovB[j], dB1);
                }
                dA0 += __shfl_xor(dA0, 32);
                dA1 += __shfl_xor(dA1, 32);
                dB0 += __shfl_xor(dB0, 32);
                dB1 += __shfl_xor(dB1, 32);
                const float eA0 = __expf(dA0), eA1 = __expf(dA1);
                const float eB0 = __expf(dB0), eB1 = __expf(dB1);
                ZA += eA0 + eA1; ZB += eB0 + eB1;
#pragma unroll
                for (int j = 0; j < 8; ++j) {
                    accA[j] = fmaf(eA0, p0[j], fmaf(eA1, p0[j + 8], accA[j]));
                    accB[j] = fmaf(eB0, p1[j], fmaf(eB1, p1[j + 8], accB[j]));
                }
            }
        }
    }

    if (MODE == 0) {
#pragma unroll
        for (int j = 0; j < 8; ++j) {
            accA[j] = cA[j] + cA[j + 8];
            accB[j] = cB[j] + cB[j + 8];
        }
    }

    {
        float* m0 = mrg + (wv * 64 + b) * MRG_PAD + 4 * hi;
        *(float4*)(m0)     = make_float4(accA[0], accA[1], accA[2], accA[3]);
        *(float4*)(m0 + 8) = make_float4(accA[4], accA[5], accA[6], accA[7]);
        float* m1 = mrg + (wv * 64 + 32 + b) * MRG_PAD + 4 * hi;
        *(float4*)(m1)     = make_float4(accB[0], accB[1], accB[2], accB[3]);
        *(float4*)(m1 + 8) = make_float4(accB[4], accB[5], accB[6], accB[7]);
        if (MODE != 0 && hi == 0) {
            float* zr = mrg + 4 * 64 * MRG_PAD;
            zr[wv * 64 + b] = ZA;
            zr[wv * 64 + 32 + b] = ZB;
        }
    }
    __syncthreads();

    // block partial -> unique slots, transposed layout pw[c][b][chunk][o]
    // (combine block (c,b) reads a contiguous 72x16 f32 run)
    {
        const int b2 = t >> 2, q = t & 3;
        float4 sum = make_float4(0.f, 0.f, 0.f, 0.f);
#pragma unroll
        for (int w2 = 0; w2 < 4; ++w2) {
            const float4 v = *(const float4*)(mrg + (w2 * 64 + b2) * MRG_PAD + q * 4);
            sum.x += v.x; sum.y += v.y; sum.z += v.z; sum.w += v.w;
        }
        float* dst = pw + (((size_t)(c * BB + b2) * NCH2 + chunk) * OO) + q * 4;
        xchf2(dst + 0, sum.x, sum.y);
        xchf2(dst + 2, sum.z, sum.w);
        if (MODE != 0 && q == 0) {
            const float* zr = mrg + 4 * 64 * MRG_PAD;
            float z = 0.f;
#pragma unroll
            for (int w2 = 0; w2 < 4; ++w2) z += zr[w2 * 64 + b2];
            xchf(pz + (size_t)(c * BB + b2) * NCH2 + chunk, z);
        }
    }

    __syncthreads();   // drain exchange acks (vmcnt) before arrival
    if (t == 0) {
        const int old = addi(flags + L_ARR(c));
        if (old == NCH2 * ph - 1) {
#pragma unroll
            for (int r = 0; r < 8; ++r) xchi(flags + L_ARREP(c, r), ph);
        }
    }
}

// ---------------- combine: block (c2,b2)=bid sums 72 chunk partials + squash ----------------
template <int MODE>
__device__ __forceinline__ void combine_phase(
    const float* __restrict__ pw, const float* __restrict__ pzw,
    const float* __restrict__ addv, float* __restrict__ dst, bool coh,
    int* flags, int bid, int t, float* cl, int ph)
{
    const int c2 = bid >> 6, b2 = bid & 63;
    const int o = t & 15, g = t >> 4;

    if (t == 0) pollge<8, (1 << 14)>(flags + L_ARREP(c2, bid & 7), ph);
    __syncthreads();   // fence: partial loads stay below the poll

    // contiguous 72x16 run for this (c2,b2)
    const float* base = pw + (size_t)(c2 * BB + b2) * NCH2 * OO;
    const float* zb   = pzw + (size_t)(c2 * BB + b2) * NCH2;
    float s = 0.f, zl = 0.f;
#pragma unroll
    for (int k = 0; k < 5; ++k) {
        const int rid = g + k * 16;
        if (rid < NCH2) {
            s += base[rid * OO + o];
            if (MODE != 0 && o == 0) zl += zb[rid];
        }
    }
    cl[t] = s;
    if (MODE != 0 && o == 0) cl[256 + g] = zl;
    __syncthreads();

    if (g == 0) {
#pragma unroll
        for (int k = 1; k < 16; ++k) s += cl[k * 16 + o];
        if (MODE != 0) {
            float Zt = 0.f;
#pragma unroll
            for (int k = 0; k < 16; ++k) Zt += cl[256 + k];
            s /= Zt;
        } else {
            s *= (1.0f / RR);
        }
        float sq = s * s;
#pragma unroll
        for (int w = 1; w < 16; w <<= 1) sq += __shfl_xor(sq, w);
        float val = s * sqrtf(sq) / (1.f + sq);
        if (MODE == 1) val += addv[(size_t)bid * OO + o];
        if (coh) xchf(dst + (size_t)bid * OO + o, val);
        else     dst[(size_t)bid * OO + o] = val;   // final out: dispatch-end flush
    }
    __syncthreads();   // drain v-write acks before completion count

    if (MODE != 2 && t == 0) {
        const int old = addi(flags + L_CD(c2));
        if (old == 64 * ph - 1) {                // 64 combine blocks per class
#pragma unroll
            for (int r = 0; r < 8; ++r) xchi(flags + L_RD(c2, r), ph);
        }
    }
}

// ---------------- fused routing kernel ----------------
// R11 config (720 blocks, 3/CU, LDS 47.2KB). R12 (6/CU grid) falsified:
// handoff traffic doubled. R13 (cross-phase x cache) falsified: scratch
// spill (+100MB traffic). R14: per-phase half-batch x register loads (see
// it_phase). W staged once from f32 (R11). XCD swizzle (R9). Flags (R10).
__global__ __launch_bounds__(256, 3) void fused_kernel(
    const int4* __restrict__ xth4, const float* __restrict__ w,
    float* pw0, float* pw1, float* pw2, float* pz1, float* pz2,
    float* v0, float* outsum, float* out, int* flags)
{
    __shared__ __align__(16) int4 wlds[WTILE_I4];   // 24576 B
    __shared__ __align__(16) float mrg[MRGF];       // 21504 B
    __shared__ float cl[272];                       //  1088 B

    const int bid = blockIdx.x;
    const int t = threadIdx.x;
    const int xcd = bid & 7;
    const int u = xcd * 90 + (bid >> 3);
    const int chunk = u / 10;
    const int c = u - chunk * 10;

    // stage the 96-route W tile f32 -> f16 [r][o][i] in LDS (12x256 float4)
    {
        const float4* wsrc = (const float4*)(w + ((size_t)c * RR + (size_t)chunk * RPB2) * 128);
        _Float16* wl = (_Float16*)wlds;
        const int i  = (t >> 2) & 7;
        const int o0 = (t & 3) * 4;
#pragma unroll 6
        for (int p = 0; p < 12; ++p) {
            const float4 v = wsrc[p * 256 + t];
            const int rp = (p * 256 + t) >> 5;
            wl[(rp * 16 + o0 + 0) * 8 + i] = (_Float16)v.x;
            wl[(rp * 16 + o0 + 1) * 8 + i] = (_Float16)v.y;
            wl[(rp * 16 + o0 + 2) * 8 + i] = (_Float16)v.z;
            wl[(rp * 16 + o0 + 3) * 8 + i] = (_Float16)v.w;
        }
    }
    __syncthreads();

    it_phase<0>(xth4, wlds, mrg, nullptr, pw0, nullptr, flags, c, chunk, xcd, t, 1);
    if (bid < CC * BB) combine_phase<0>(pw0, nullptr, nullptr, v0, true, flags, bid, t, cl, 1);
    it_phase<1>(xth4, wlds, mrg, v0, pw1, pz1, flags, c, chunk, xcd, t, 2);
    if (bid < CC * BB) combine_phase<1>(pw1, pz1, v0, outsum, true, flags, bid, t, cl, 2);
    it_phase<2>(xth4, wlds, mrg, outsum, pw2, pz2, flags, c, chunk, xcd, t, 3);
    if (bid < CC * BB) combine_phase<2>(pw2, pz2, nullptr, out, false, flags, bid, t, cl, 3);
}

extern "C" void kernel_launch(void* const* d_in, const int* in_sizes, int n_in,
                              void* d_out, int out_size, void* d_ws, size_t ws_size,
                              hipStream_t stream)
{
    const float* x = (const float*)d_in[0];
    const float* w = (const float*)d_in[1];
    float* out = (float*)d_out;

    float* ws = (float*)d_ws;
    float* xth    = ws;                                   // RR*BB*4 f32 slots (f16 x2)
    float* pw0    = xth + (size_t)RR * BB * 4;            // PWW
    float* pw1    = pw0 + PWW;                            // PWW
    float* pw2    = pw1 + PWW;                            // PWW
    float* pz1    = pw2 + PWW;                            // PZW
    float* pz2    = pz1 + PZW;                            // PZW
    float* v0     = pz2 + PZW;                            // CC*BB*OO
    float* outsum = v0 + CC * BB * OO;                    // CC*BB*OO
    int*   flags  = (int*)(outsum + CC * BB * OO);        // FLAGI ints

    int4* xth4 = (int4*)xth;

    prep_kernel<<<dim3(432), dim3(256), 0, stream>>>(x, xth4, flags);
    fused_kernel<<<dim3(NBLK), dim3(256), 0, stream>>>(
        xth4, w, pw0, pw1, pw2, pz1, pz2, v0, outsum, out, flags);
}